// Round 1
// baseline (1149.598 us; speedup 1.0000x reference)
//
#include <hip/hip_runtime.h>
#include <stdint.h>

// NeuralMemoryLinear on MI355X (gfx950), bf16 MFMA implementation.
// b=2, L=2048, dim=1024, n=8, dh=128.
//
// Pipeline:
//  k_hbt   : hidden f32 -> hbT bf16 transposed [b, hd, d]
//  k_lrwd  : lr[b,n,l], lwd[b,n,l] (f32) from x @ fc_{lr,wd}_w + bias
//  k_scan  : wdc = exp(cumsum lwd), wdlast[l] = exp(lwd[L-1]*min(l+1,L-1))
//  g1_qkv  : Q,K,V bf16 = x @ {wq,wk,wv} + bias  (f32 sources staged->bf16)
//  k_qs    : Qs = Q * wdc (bf16)
//  g2_s    : S[b,n,m,l] = -(q_m.k_l)*exp(lwd[m]*min(l+1,m)) for l<=m (bf16),
//            blocks with l0 > m0+63 skipped entirely (never read either)
//  g3_af   : Afold[b,n,l,d] = (K_n @ W_prev_n^T - v) * lr  (bf16)
//  g4_y    : y[b,m,d] = sum_n sum_{l<=m} S*Afold + sum_hd Qs*hbT   (f32 out)
//  g5_wn   : W_next[b,d,hd] = hidden*wdc_last - sum_l Afold*wdlast*k (f32 out)
//
// Workspace: ~240 MB (see kernel_launch offsets).

typedef __bf16 bf16x8 __attribute__((ext_vector_type(8)));
typedef float f32x4 __attribute__((ext_vector_type(4)));
typedef uint32_t u32x4 __attribute__((ext_vector_type(4)));
typedef unsigned short u16;

#define MFMA16 __builtin_amdgcn_mfma_f32_16x16x32_bf16

static __device__ __forceinline__ u16 f2b(float f) {
  union { float f; uint32_t u; } v; v.f = f;
  uint32_t r = v.u + 0x7FFFu + ((v.u >> 16) & 1u);
  return (u16)(r >> 16);
}
static __device__ __forceinline__ float b2f(u16 h) {
  union { uint32_t u; float f; } v; v.u = ((uint32_t)h) << 16;
  return v.f;
}

// ---------------- GEMM skeleton pieces (64x64 tile, BK=32, 256 thr = 4 waves)
// LDS tiles padded to 40 shorts/row (80 B) to break bank-conflict strides.

// A row-major [M][K] bf16 source, caller pre-offsets to (m0,k0).
static __device__ __forceinline__ void stageA_direct(u16 As[][40], const u16* __restrict__ A,
                                                     int lda, int t) {
  const int tr = t >> 2, tc = (t & 3) << 3;
  *(u32x4*)(&As[tr][tc]) = *(const u32x4*)(A + (size_t)tr * lda + tc);
}
// A row-major [M][K] f32 source -> bf16
static __device__ __forceinline__ void stageA_direct_f32(u16 As[][40], const float* __restrict__ A,
                                                         int lda, int t) {
  const int tr = t >> 2, tc = (t & 3) << 3;
  const float* src = A + (size_t)tr * lda + tc;
  u16 tmp[8];
#pragma unroll
  for (int j = 0; j < 8; ++j) tmp[j] = f2b(src[j]);
  *(u32x4*)(&As[tr][tc]) = *(const u32x4*)tmp;
}
// A supplied as A^T row-major [K][M] bf16 (e.g. Afold for g5): transpose on stage.
static __device__ __forceinline__ void stageA_trans(u16 As[][40], const u16* __restrict__ At,
                                                    int ldat, int t) {
  const int kk = t >> 3, mg = (t & 7) << 3;
  u32x4 val = *(const u32x4*)(At + (size_t)kk * ldat + mg);
  u16 tmp[8]; *(u32x4*)tmp = val;
#pragma unroll
  for (int j = 0; j < 8; ++j) As[mg + j][kk] = tmp[j];
}
// B row-major [K][N] bf16: transpose into Bts[n][k].
static __device__ __forceinline__ void stageB_trans(u16 Bts[][40], const u16* __restrict__ B,
                                                    int ldb, int t) {
  const int kk = t >> 3, ng = (t & 7) << 3;
  u32x4 val = *(const u32x4*)(B + (size_t)kk * ldb + ng);
  u16 tmp[8]; *(u32x4*)tmp = val;
#pragma unroll
  for (int j = 0; j < 8; ++j) Bts[ng + j][kk] = tmp[j];
}
// B row-major [K][N] f32 source
static __device__ __forceinline__ void stageB_trans_f32(u16 Bts[][40], const float* __restrict__ B,
                                                        int ldb, int t) {
  const int kk = t >> 3, ng = (t & 7) << 3;
  const float* src = B + (size_t)kk * ldb + ng;
#pragma unroll
  for (int j = 0; j < 8; ++j) Bts[ng + j][kk] = f2b(src[j]);
}
// B row-major [K][N] bf16 with per-k row scale (g5: k * wdlast[l])
static __device__ __forceinline__ void stageB_trans_scaled(u16 Bts[][40], const u16* __restrict__ B,
                                                           int ldb, const float* __restrict__ scale,
                                                           int t) {
  const int kk = t >> 3, ng = (t & 7) << 3;
  u32x4 val = *(const u32x4*)(B + (size_t)kk * ldb + ng);
  u16 tmp[8]; *(u32x4*)tmp = val;
  const float sc = scale[kk];
#pragma unroll
  for (int j = 0; j < 8; ++j) Bts[ng + j][kk] = f2b(b2f(tmp[j]) * sc);
}
// B supplied as B^T row-major [N][K] bf16 (g2: kb rows are l): direct copy.
static __device__ __forceinline__ void stageBT_direct(u16 Bts[][40], const u16* __restrict__ Bt,
                                                      int ldbt, int t) {
  const int nr = t >> 2, kg = (t & 3) << 3;
  *(u32x4*)(&Bts[nr][kg]) = *(const u32x4*)(Bt + (size_t)nr * ldbt + kg);
}

// One BK=32 step: wave (wr,wc) does 2x2 MFMA 16x16x32 tiles.
// A frag: A[m=lane&15][k=quad*8+j]; B frag: B[k=quad*8+j][n=lane&15];
// C/D: col=lane&15, row=quad*4+reg  [verified layouts, learn_hip m89/m91/m118]
static __device__ __forceinline__ void mfma_step(const u16 As[][40], const u16 Bts[][40],
                                                 int wr, int wc, int q8, int r, f32x4 acc[2][2]) {
  bf16x8 a0 = *(const bf16x8*)(&As[wr + r][q8]);
  bf16x8 a1 = *(const bf16x8*)(&As[wr + 16 + r][q8]);
  bf16x8 b0 = *(const bf16x8*)(&Bts[wc + r][q8]);
  bf16x8 b1 = *(const bf16x8*)(&Bts[wc + 16 + r][q8]);
  acc[0][0] = MFMA16(a0, b0, acc[0][0], 0, 0, 0);
  acc[0][1] = MFMA16(a0, b1, acc[0][1], 0, 0, 0);
  acc[1][0] = MFMA16(a1, b0, acc[1][0], 0, 0, 0);
  acc[1][1] = MFMA16(a1, b1, acc[1][1], 0, 0, 0);
}

#define WAVE_IDS                                 \
  const int t = threadIdx.x;                     \
  const int w = t >> 6, ln = t & 63;             \
  const int wr = (w >> 1) << 5, wc = (w & 1) << 5; \
  const int q = ln >> 4, q8 = q << 3, r = ln & 15;

// ---------------- small kernels ----------------

// hidden [b,d,hd] f32 -> hbT [b,hd,d] bf16
__global__ __launch_bounds__(256) void k_hbt(const float* __restrict__ hidden, u16* __restrict__ hbT) {
  __shared__ float tile[32][33];
  const int b = blockIdx.z;
  const int hd0 = blockIdx.x * 32, d0 = blockIdx.y * 32;
  const int tx = threadIdx.x, ty = threadIdx.y;  // 32 x 8
#pragma unroll
  for (int i = 0; i < 4; ++i)
    tile[ty + i * 8][tx] = hidden[((size_t)b * 1024 + d0 + ty + i * 8) * 1024 + hd0 + tx];
  __syncthreads();
#pragma unroll
  for (int i = 0; i < 4; ++i)
    hbT[((size_t)b * 1024 + hd0 + ty + i * 8) * 1024 + d0 + tx] = f2b(tile[tx][ty + i * 8]);
}

// lr[b,n,l] = exp(lbl[n]) * sigmoid(x@fc_lr_w + b); lwd = log1p(-exp(lbw)*sigmoid(...))
__global__ __launch_bounds__(256) void k_lrwd(const float* __restrict__ x,
    const float* __restrict__ wlr, const float* __restrict__ blr,
    const float* __restrict__ wwd, const float* __restrict__ bwd,
    const float* __restrict__ lbl, const float* __restrict__ lbw,
    float* __restrict__ lr, float* __restrict__ lwd) {
  const int row = blockIdx.x;  // b*2048 + l
  const int t = threadIdx.x;
  float pl[8] = {0.f, 0.f, 0.f, 0.f, 0.f, 0.f, 0.f, 0.f};
  float pw[8] = {0.f, 0.f, 0.f, 0.f, 0.f, 0.f, 0.f, 0.f};
  const float* xr = x + (size_t)row * 1024;
  for (int i = t; i < 1024; i += 256) {
    const float xv = xr[i];
    const float* wl = wlr + (size_t)i * 8;
    const float* ww = wwd + (size_t)i * 8;
#pragma unroll
    for (int j = 0; j < 8; ++j) { pl[j] += xv * wl[j]; pw[j] += xv * ww[j]; }
  }
  __shared__ float red[256][17];
#pragma unroll
  for (int j = 0; j < 8; ++j) { red[t][j] = pl[j]; red[t][j + 8] = pw[j]; }
  __syncthreads();
  for (int s = 128; s > 0; s >>= 1) {
    if (t < s) {
#pragma unroll
      for (int j = 0; j < 16; ++j) red[t][j] += red[t + s][j];
    }
    __syncthreads();
  }
  const int b = row >> 11, l = row & 2047;
  if (t < 8) {
    const float s1 = red[0][t] + blr[t];
    const float sig = 1.f / (1.f + expf(-s1));
    lr[((size_t)b * 8 + t) * 2048 + l] = expf(lbl[t]) * sig;
  } else if (t < 16) {
    const int j = t - 8;
    const float s2 = red[0][t] + bwd[j];
    const float sig = 1.f / (1.f + expf(-s2));
    lwd[((size_t)b * 8 + j) * 2048 + l] = log1pf(-expf(lbw[j]) * sig);
  }
}

// per (b,n): wdc = exp(inclusive cumsum lwd); wdlast[l] = exp(lwd[L-1]*min(l+1, L-1))
__global__ __launch_bounds__(256) void k_scan(const float* __restrict__ lwd,
                                              float* __restrict__ wdc, float* __restrict__ wdlast) {
  const int bn = blockIdx.x, t = threadIdx.x;
  const float* src = lwd + (size_t)bn * 2048;
  float v[8], s = 0.f;
#pragma unroll
  for (int i = 0; i < 8; ++i) { v[i] = src[t * 8 + i]; s += v[i]; }
  __shared__ float ps[256];
  ps[t] = s;
  __syncthreads();
  for (int off = 1; off < 256; off <<= 1) {
    const float add = (t >= off) ? ps[t - off] : 0.f;
    __syncthreads();
    ps[t] += add;
    __syncthreads();
  }
  float run = ps[t] - s;  // exclusive prefix
  const float lwd_last = src[2047];
  float* wo = wdc + (size_t)bn * 2048;
  float* wl = wdlast + (size_t)bn * 2048;
#pragma unroll
  for (int i = 0; i < 8; ++i) {
    run += v[i];
    const int idx = t * 8 + i;
    wo[idx] = expf(run);
    const int c = (idx + 1 < 2047) ? (idx + 1) : 2047;
    wl[idx] = expf(lwd_last * (float)c);
  }
}

// Qs = Q * wdc[b, hd>>7, m]
__global__ __launch_bounds__(256) void k_qs(const u16* __restrict__ qb,
                                            const float* __restrict__ wdc, u16* __restrict__ Qs) {
  const size_t base = ((size_t)blockIdx.x * 256 + threadIdx.x) * 4;
  if (base >= (size_t)4194304) return;
  const int b = (int)(base >> 21);
  const int rem = (int)(base & 2097151);
  const int m = rem >> 10, hd = rem & 1023;
  const float sc = wdc[((size_t)b * 8 + (hd >> 7)) * 2048 + m];
  const uint32_t* p = (const uint32_t*)(qb + base);
  const uint32_t w0 = p[0], w1 = p[1];
  uint32_t r0, r1;
  r0 = (uint32_t)f2b(b2f((u16)(w0 & 0xFFFFu)) * sc);
  r0 |= ((uint32_t)f2b(b2f((u16)(w0 >> 16)) * sc)) << 16;
  r1 = (uint32_t)f2b(b2f((u16)(w1 & 0xFFFFu)) * sc);
  r1 |= ((uint32_t)f2b(b2f((u16)(w1 >> 16)) * sc)) << 16;
  uint32_t* o = (uint32_t*)(Qs + base);
  o[0] = r0; o[1] = r1;
}

// ---------------- GEMM kernels ----------------

// Q/K/V = x @ {wq,wk,wv} + bias, bf16 out. grid (64,16,3)
__global__ __launch_bounds__(256) void g1_qkv(const float* __restrict__ x,
    const float* __restrict__ wq, const float* __restrict__ wk, const float* __restrict__ wv,
    const float* __restrict__ bq, const float* __restrict__ bk, const float* __restrict__ bv,
    u16* __restrict__ qb, u16* __restrict__ kb, u16* __restrict__ vb) {
  __shared__ u16 As[64][40], Bts[64][40];
  WAVE_IDS
  const int m0 = blockIdx.x * 64, n0 = blockIdx.y * 64, z = blockIdx.z;
  const float* W = (z == 0) ? wq : (z == 1) ? wk : wv;
  const float* bias = (z == 0) ? bq : (z == 1) ? bk : bv;
  u16* outp = (z == 0) ? qb : (z == 1) ? kb : vb;
  f32x4 acc[2][2] = {};
  for (int k0 = 0; k0 < 1024; k0 += 32) {
    __syncthreads();
    stageA_direct_f32(As, x + (size_t)m0 * 1024 + k0, 1024, t);
    stageB_trans_f32(Bts, W + (size_t)k0 * 1024 + n0, 1024, t);
    __syncthreads();
    mfma_step(As, Bts, wr, wc, q8, r, acc);
  }
#pragma unroll
  for (int sm = 0; sm < 2; ++sm)
#pragma unroll
    for (int sn = 0; sn < 2; ++sn) {
      const int gcol = n0 + wc + sn * 16 + r;
      const float bv_ = bias[gcol];
#pragma unroll
      for (int i = 0; i < 4; ++i) {
        const int grow = m0 + wr + sm * 16 + (q << 2) + i;
        outp[(size_t)grow * 1024 + gcol] = f2b(acc[sm][sn][i] + bv_);
      }
    }
}

// S[b,n,m,l] = -(q_m . k_l) * exp(lwd[m]*min(l+1,m)) for l<=m, else 0. grid (32,32,16)
__global__ __launch_bounds__(256) void g2_s(const u16* __restrict__ qb, const u16* __restrict__ kb,
                                            const float* __restrict__ lwd, u16* __restrict__ S) {
  const int bn = blockIdx.z, b = bn >> 3, n = bn & 7;
  const int m0 = blockIdx.x * 64, l0 = blockIdx.y * 64;
  if (l0 > m0) return;  // strictly-upper blocks never written nor read
  __shared__ u16 As[64][40], Bts[64][40];
  WAVE_IDS
  f32x4 acc[2][2] = {};
  const u16* Ab = qb + ((size_t)b * 2048 + m0) * 1024 + n * 128;
  const u16* Bb = kb + ((size_t)b * 2048 + l0) * 1024 + n * 128;
  for (int k0 = 0; k0 < 128; k0 += 32) {
    __syncthreads();
    stageA_direct(As, Ab + k0, 1024, t);
    stageBT_direct(Bts, Bb + k0, 1024, t);
    __syncthreads();
    mfma_step(As, Bts, wr, wc, q8, r, acc);
  }
  const float* lwdrow = lwd + (size_t)bn * 2048;
  u16* Sb = S + (size_t)bn * 2048 * 2048;
#pragma unroll
  for (int sm = 0; sm < 2; ++sm)
#pragma unroll
    for (int i = 0; i < 4; ++i) {
      const int m = m0 + wr + sm * 16 + (q << 2) + i;
      const float lm = lwdrow[m];
#pragma unroll
      for (int sn = 0; sn < 2; ++sn) {
        const int l = l0 + wc + sn * 16 + r;
        float v = 0.f;
        if (l <= m) {
          const float c = (l == m) ? (float)m : (float)(l + 1);
          v = -acc[sm][sn][i] * expf(lm * c);
        }
        Sb[(size_t)m * 2048 + l] = f2b(v);
      }
    }
}

// Afold[b,n,l,d] = (sum_h k[l,h]*hbT[n*128+h,d] - v[l,d]) * lr[b,n,l]. grid (32,16,16)
__global__ __launch_bounds__(256) void g3_af(const u16* __restrict__ kb, const u16* __restrict__ hbT,
                                             const u16* __restrict__ vb, const float* __restrict__ lr,
                                             u16* __restrict__ Afold) {
  const int bn = blockIdx.z, b = bn >> 3, n = bn & 7;
  const int m0 = blockIdx.x * 64, n0 = blockIdx.y * 64;  // m0: l, n0: d
  __shared__ u16 As[64][40], Bts[64][40];
  WAVE_IDS
  f32x4 acc[2][2] = {};
  for (int k0 = 0; k0 < 128; k0 += 32) {
    __syncthreads();
    stageA_direct(As, kb + ((size_t)b * 2048 + m0) * 1024 + n * 128 + k0, 1024, t);
    stageB_trans(Bts, hbT + ((size_t)b * 1024 + n * 128 + k0) * 1024 + n0, 1024, t);
    __syncthreads();
    mfma_step(As, Bts, wr, wc, q8, r, acc);
  }
  const float* lrrow = lr + (size_t)bn * 2048;
#pragma unroll
  for (int sm = 0; sm < 2; ++sm)
#pragma unroll
    for (int i = 0; i < 4; ++i) {
      const int l = m0 + wr + sm * 16 + (q << 2) + i;
      const float lrv = lrrow[l];
#pragma unroll
      for (int sn = 0; sn < 2; ++sn) {
        const int d = n0 + wc + sn * 16 + r;
        const float v = (acc[sm][sn][i] - b2f(vb[((size_t)b * 2048 + l) * 1024 + d])) * lrv;
        Afold[((size_t)bn * 2048 + l) * 1024 + d] = f2b(v);
      }
    }
}

// y[b,m,d] = sum_n sum_{l<=m} S*Afold + sum_hd Qs*hbT. grid (32,16,2)
__global__ __launch_bounds__(256) void g4_y(const u16* __restrict__ S, const u16* __restrict__ Afold,
                                            const u16* __restrict__ Qs, const u16* __restrict__ hbT,
                                            float* __restrict__ y) {
  const int b = blockIdx.z;
  const int m0 = blockIdx.x * 64, d0 = blockIdx.y * 64;
  __shared__ u16 As[64][40], Bts[64][40];
  WAVE_IDS
  f32x4 acc[2][2] = {};
  const int nk = 2 * (blockIdx.x + 1);  // l-chunks of 32 with l0 <= m0+63
  for (int n = 0; n < 8; ++n) {
    const u16* Sseg = S + (size_t)(b * 8 + n) * 2048 * 2048 + (size_t)m0 * 2048;
    const u16* Bseg = Afold + (size_t)(b * 8 + n) * 2048 * 1024;
    for (int c = 0; c < nk; ++c) {
      const int k0 = c * 32;
      __syncthreads();
      stageA_direct(As, Sseg + k0, 2048, t);
      stageB_trans(Bts, Bseg + (size_t)k0 * 1024 + d0, 1024, t);
      __syncthreads();
      mfma_step(As, Bts, wr, wc, q8, r, acc);
    }
  }
  const u16* Qsb = Qs + (size_t)b * 2048 * 1024 + (size_t)m0 * 1024;
  const u16* Hb = hbT + (size_t)b * 1024 * 1024;
  for (int k0 = 0; k0 < 1024; k0 += 32) {
    __syncthreads();
    stageA_direct(As, Qsb + k0, 1024, t);
    stageB_trans(Bts, Hb + (size_t)k0 * 1024 + d0, 1024, t);
    __syncthreads();
    mfma_step(As, Bts, wr, wc, q8, r, acc);
  }
#pragma unroll
  for (int sm = 0; sm < 2; ++sm)
#pragma unroll
    for (int sn = 0; sn < 2; ++sn) {
      const int gcol = d0 + wc + sn * 16 + r;
#pragma unroll
      for (int i = 0; i < 4; ++i) {
        const int m = m0 + wr + sm * 16 + (q << 2) + i;
        y[((size_t)b * 2048 + m) * 1024 + gcol] = acc[sm][sn][i];
      }
    }
}

// W_next[b,d,n*128+h] = hidden*wdc_last - sum_l Afold[l,d]*wdlast[l]*k[l,h]. grid (16,2,16)
__global__ __launch_bounds__(256) void g5_wn(const u16* __restrict__ Afold, const u16* __restrict__ kb,
                                             const float* __restrict__ wdlast, const float* __restrict__ wdc,
                                             const float* __restrict__ hidden, float* __restrict__ outw) {
  const int bn = blockIdx.z, b = bn >> 3, n = bn & 7;
  const int m0 = blockIdx.x * 64;  // d
  const int n0 = blockIdx.y * 64;  // h
  __shared__ u16 As[64][40], Bts[64][40];
  WAVE_IDS
  f32x4 acc[2][2] = {};
  for (int k0 = 0; k0 < 2048; k0 += 32) {
    __syncthreads();
    stageA_trans(As, Afold + ((size_t)bn * 2048 + k0) * 1024 + m0, 1024, t);
    stageB_trans_scaled(Bts, kb + ((size_t)b * 2048 + k0) * 1024 + n * 128 + n0, 1024,
                        wdlast + (size_t)bn * 2048 + k0, t);
    __syncthreads();
    mfma_step(As, Bts, wr, wc, q8, r, acc);
  }
  const float wdcl = wdc[(size_t)bn * 2048 + 2047];
#pragma unroll
  for (int sm = 0; sm < 2; ++sm)
#pragma unroll
    for (int sn = 0; sn < 2; ++sn) {
      const int h = n0 + wc + sn * 16 + r;
#pragma unroll
      for (int i = 0; i < 4; ++i) {
        const int d = m0 + wr + sm * 16 + (q << 2) + i;
        const size_t off = ((size_t)b * 1024 + d) * 1024 + n * 128 + h;
        outw[off] = hidden[off] * wdcl - acc[sm][sn][i];
      }
    }
}

// ---------------- launch ----------------

extern "C" void kernel_launch(void* const* d_in, const int* in_sizes, int n_in,
                              void* d_out, int out_size, void* d_ws, size_t ws_size,
                              hipStream_t stream) {
  const float* x      = (const float*)d_in[0];
  const float* hidden = (const float*)d_in[1];
  const float* lbl    = (const float*)d_in[2];
  const float* wlr    = (const float*)d_in[3];
  const float* blr    = (const float*)d_in[4];
  const float* lbw    = (const float*)d_in[5];
  const float* wwd    = (const float*)d_in[6];
  const float* bwd    = (const float*)d_in[7];
  const float* wq     = (const float*)d_in[8];
  const float* bq     = (const float*)d_in[9];
  const float* wk     = (const float*)d_in[10];
  const float* bk     = (const float*)d_in[11];
  const float* wv     = (const float*)d_in[12];
  const float* bv     = (const float*)d_in[13];
  float* out = (float*)d_out;

  char* ws = (char*)d_ws;
  size_t off = 0;
  auto alloc = [&](size_t bytes) { char* p = ws + off; off += bytes; return p; };
  u16* hbT    = (u16*)alloc((size_t)2 * 1024 * 1024 * 2);       // 4 MB
  u16* qb     = (u16*)alloc((size_t)4096 * 1024 * 2);           // 8 MB
  u16* kb     = (u16*)alloc((size_t)4096 * 1024 * 2);           // 8 MB
  u16* vb     = (u16*)alloc((size_t)4096 * 1024 * 2);           // 8 MB
  u16* Qs     = (u16*)alloc((size_t)4096 * 1024 * 2);           // 8 MB
  float* lr   = (float*)alloc((size_t)16 * 2048 * 4);
  float* lwd  = (float*)alloc((size_t)16 * 2048 * 4);
  float* wdc  = (float*)alloc((size_t)16 * 2048 * 4);
  float* wdl  = (float*)alloc((size_t)16 * 2048 * 4);
  u16* Afold  = (u16*)alloc((size_t)16 * 2048 * 1024 * 2);      // 64 MB
  u16* S      = (u16*)alloc((size_t)16 * 2048 * 2048 * 2);      // 128 MB
  (void)ws_size; (void)n_in; (void)in_sizes; (void)out_size;    // total ~240 MB

  const size_t YSZ = (size_t)2 * 2048 * 1024;

  k_hbt<<<dim3(32, 32, 2), dim3(32, 8), 0, stream>>>(hidden, hbT);
  k_lrwd<<<4096, 256, 0, stream>>>(x, wlr, blr, wwd, bwd, lbl, lbw, lr, lwd);
  k_scan<<<16, 256, 0, stream>>>(lwd, wdc, wdl);
  g1_qkv<<<dim3(64, 16, 3), 256, 0, stream>>>(x, wq, wk, wv, bq, bk, bv, qb, kb, vb);
  k_qs<<<4096, 256, 0, stream>>>(qb, wdc, Qs);
  g2_s<<<dim3(32, 32, 16), 256, 0, stream>>>(qb, kb, lwd, S);
  g3_af<<<dim3(32, 16, 16), 256, 0, stream>>>(kb, hbT, vb, lr, Afold);
  g4_y<<<dim3(32, 16, 2), 256, 0, stream>>>(S, Afold, Qs, hbT, out);
  g5_wn<<<dim3(16, 2, 16), 256, 0, stream>>>(Afold, kb, wdl, wdc, hidden, out + YSZ);
}

// Round 3
// 504.621 us; speedup vs baseline: 2.2781x; 2.2781x over previous
//
#include <hip/hip_runtime.h>
#include <stdint.h>

// NeuralMemoryLinear on MI355X (gfx950). b=2, L=2048, dim=1024, n=8, dh=128.
// R3: R2 structure (128x128 tile, BK=32, global_load_lds 16B, unpadded LDS,
// 4 waves x 4x4 16x16x32 bf16 MFMA) with two fixes:
//  - gld16 uses a proper generic->AS3 addrspacecast (R2 truncated the flat
//    pointer to 32 bits -> DMA to garbage LDS address -> abort)
//  - workspace capped at 228.5 MB (R1's proven-good footprint) via live-range
//    overlap; g4 partials atomicAdd into pre-zeroed y (no Yp buffer).

typedef __bf16 bf16x8 __attribute__((ext_vector_type(8)));
typedef float f32x4 __attribute__((ext_vector_type(4)));
typedef unsigned short u16;
typedef u16 u16x4 __attribute__((ext_vector_type(4)));

#define MFMA16 __builtin_amdgcn_mfma_f32_16x16x32_bf16

static __device__ __forceinline__ u16 f2b(float f) {
  union { float f; uint32_t u; } v; v.f = f;
  uint32_t r = v.u + 0x7FFFu + ((v.u >> 16) & 1u);
  return (u16)(r >> 16);
}
static __device__ __forceinline__ float b2f(u16 h) {
  union { uint32_t u; float f; } v; v.u = ((uint32_t)h) << 16;
  return v.f;
}

// ---- async global->LDS, 16B per lane. LDS dest = wave-uniform base + lane*16.
typedef __attribute__((address_space(1))) void gvoid_t;
typedef __attribute__((address_space(3))) void lvoid_t;
static __device__ __forceinline__ void gld16(const u16* g, u16* l) {
  // global AS == flat numerically; LDS needs a real addrspacecast (NOT a
  // 32-bit truncation of the flat address).
  __builtin_amdgcn_global_load_lds((gvoid_t*)(uintptr_t)g, (lvoid_t*)l, 16, 0, 0);
}
// Stage a 128x32 u16 tile (row-major, leading dim ld) into unpadded LDS [128][32].
// Byte offset of thread t = t*16 (+4096 for second issue): wave-uniform + lane*16.
static __device__ __forceinline__ void stage(u16* lds, const u16* __restrict__ g, int ld, int t) {
  const int r0 = t >> 2, c0 = (t & 3) << 3;
  gld16(g + (size_t)r0 * ld + c0, lds + (r0 << 5) + c0);
  gld16(g + (size_t)(r0 + 64) * ld + c0, lds + ((r0 + 64) << 5) + c0);
}

// 4 waves in 2x2; each wave 64x64 = 4x4 MFMA subtiles.
#define TILE_IDS                                   \
  const int t = threadIdx.x;                       \
  const int w = t >> 6, ln = t & 63;               \
  const int wr = (w >> 1) << 6, wc = (w & 1) << 6; \
  const int q = ln >> 4, q8 = q << 3, r = ln & 15;

static __device__ __forceinline__ void mfma_tile(const u16* As, const u16* Bs,
                                                 int wr, int wc, int q8, int r, f32x4 acc[4][4]) {
  bf16x8 af[4], bf[4];
#pragma unroll
  for (int s = 0; s < 4; ++s) af[s] = *(const bf16x8*)(As + ((wr + s * 16 + r) << 5) + q8);
#pragma unroll
  for (int s = 0; s < 4; ++s) bf[s] = *(const bf16x8*)(Bs + ((wc + s * 16 + r) << 5) + q8);
#pragma unroll
  for (int sm = 0; sm < 4; ++sm)
#pragma unroll
    for (int sn = 0; sn < 4; ++sn)
      acc[sm][sn] = MFMA16(af[sm], bf[sn], acc[sm][sn], 0, 0, 0);
}
// acc element (sm, sn, i): row = wr+sm*16+q*4+i, col = wc+sn*16+r.

// ---------------- small kernels ----------------

__global__ __launch_bounds__(256) void k_cast(const float* __restrict__ s, u16* __restrict__ d) {
  const size_t i = ((size_t)blockIdx.x * 256 + threadIdx.x) * 4;
  f32x4 v = *(const f32x4*)(s + i);
  u16x4 o;
#pragma unroll
  for (int j = 0; j < 4; ++j) o[j] = f2b(v[j]);
  *(u16x4*)(d + i) = o;
}

__global__ __launch_bounds__(256) void k_zero(float* __restrict__ p) {
  const size_t i = ((size_t)blockIdx.x * 256 + threadIdx.x) * 4;
  *(f32x4*)(p + i) = f32x4{0.f, 0.f, 0.f, 0.f};
}

// transpose-cast 1024x1024 f32 w[k][n] -> bf16 wT[n][k], z selects q/k/v
__global__ __launch_bounds__(256) void k_twt(const float* __restrict__ wq, const float* __restrict__ wk,
                                             const float* __restrict__ wv, u16* __restrict__ wqT,
                                             u16* __restrict__ wkT, u16* __restrict__ wvT) {
  const int z = blockIdx.z;
  const float* src = z == 0 ? wq : z == 1 ? wk : wv;
  u16* dst = z == 0 ? wqT : z == 1 ? wkT : wvT;
  __shared__ float tile[32][33];
  const int k0 = blockIdx.x * 32, n0 = blockIdx.y * 32;
  const int tx = threadIdx.x, ty = threadIdx.y;
#pragma unroll
  for (int i = 0; i < 4; ++i)
    tile[ty + i * 8][tx] = src[(size_t)(k0 + ty + i * 8) * 1024 + n0 + tx];
  __syncthreads();
#pragma unroll
  for (int i = 0; i < 4; ++i)
    dst[(size_t)(n0 + ty + i * 8) * 1024 + k0 + tx] = f2b(tile[tx][ty + i * 8]);
}

__global__ __launch_bounds__(256) void k_lrwd(const float* __restrict__ x,
    const float* __restrict__ wlr, const float* __restrict__ blr,
    const float* __restrict__ wwd, const float* __restrict__ bwd,
    const float* __restrict__ lbl, const float* __restrict__ lbw,
    float* __restrict__ lr, float* __restrict__ lwd) {
  const int row = blockIdx.x;  // b*2048 + l
  const int t = threadIdx.x;
  float pl[8] = {}, pw[8] = {};
  const float* xr = x + (size_t)row * 1024;
  for (int i = t; i < 1024; i += 256) {
    const float xv = xr[i];
    const float* wl = wlr + (size_t)i * 8;
    const float* ww = wwd + (size_t)i * 8;
#pragma unroll
    for (int j = 0; j < 8; ++j) { pl[j] += xv * wl[j]; pw[j] += xv * ww[j]; }
  }
  __shared__ float red[256][17];
#pragma unroll
  for (int j = 0; j < 8; ++j) { red[t][j] = pl[j]; red[t][j + 8] = pw[j]; }
  __syncthreads();
  for (int s = 128; s > 0; s >>= 1) {
    if (t < s) {
#pragma unroll
      for (int j = 0; j < 16; ++j) red[t][j] += red[t + s][j];
    }
    __syncthreads();
  }
  const int b = row >> 11, l = row & 2047;
  if (t < 8) {
    const float sig = 1.f / (1.f + expf(-(red[0][t] + blr[t])));
    lr[((size_t)b * 8 + t) * 2048 + l] = expf(lbl[t]) * sig;
  } else if (t < 16) {
    const int j = t - 8;
    const float sig = 1.f / (1.f + expf(-(red[0][t] + bwd[j])));
    lwd[((size_t)b * 8 + j) * 2048 + l] = log1pf(-expf(lbw[j]) * sig);
  }
}

__global__ __launch_bounds__(256) void k_scan(const float* __restrict__ lwd,
                                              float* __restrict__ wdc, float* __restrict__ wdlast) {
  const int bn = blockIdx.x, t = threadIdx.x;
  const float* src = lwd + (size_t)bn * 2048;
  float v[8], s = 0.f;
#pragma unroll
  for (int i = 0; i < 8; ++i) { v[i] = src[t * 8 + i]; s += v[i]; }
  __shared__ float ps[256];
  ps[t] = s;
  __syncthreads();
  for (int off = 1; off < 256; off <<= 1) {
    const float add = (t >= off) ? ps[t - off] : 0.f;
    __syncthreads();
    ps[t] += add;
    __syncthreads();
  }
  float run = ps[t] - s;
  const float lwd_last = src[2047];
  float* wo = wdc + (size_t)bn * 2048;
  float* wl = wdlast + (size_t)bn * 2048;
#pragma unroll
  for (int i = 0; i < 8; ++i) {
    run += v[i];
    const int idx = t * 8 + i;
    wo[idx] = expf(run);
    const int c = (idx + 1 < 2047) ? (idx + 1) : 2047;
    wl[idx] = expf(lwd_last * (float)c);
  }
}

// in-place: qb *= wdc[b, head(hd), m]  (4 elems/thread; groups never cross heads)
__global__ __launch_bounds__(256) void k_qs(u16* __restrict__ qb, const float* __restrict__ wdc) {
  const size_t base = ((size_t)blockIdx.x * 256 + threadIdx.x) * 4;
  const int b = (int)(base >> 21);
  const int rem = (int)(base & 2097151);
  const int m = rem >> 10, hd = rem & 1023;
  const float sc = wdc[((size_t)b * 8 + (hd >> 7)) * 2048 + m];
  u16x4 v = *(const u16x4*)(qb + base);
#pragma unroll
  for (int j = 0; j < 4; ++j) v[j] = f2b(b2f(v[j]) * sc);
  *(u16x4*)(qb + base) = v;
}

// ---------------- GEMM kernels ----------------

// q,k: [4096 x 1024] = xb @ w^T + bias. z=0: q, z=1: k.
__global__ __launch_bounds__(256) void g_qk(const u16* __restrict__ xb, const u16* __restrict__ wqT,
    const u16* __restrict__ wkT, const float* __restrict__ bq, const float* __restrict__ bk,
    u16* __restrict__ qb, u16* __restrict__ kb) {
  __shared__ u16 As[4096], Bs[4096];
  TILE_IDS
  const int m0 = blockIdx.x * 128, n0 = blockIdx.y * 128, z = blockIdx.z;
  const u16* A = xb + (size_t)m0 * 1024;
  const u16* B = (z ? wkT : wqT) + (size_t)n0 * 1024;
  const float* bias = z ? bk : bq;
  u16* outp = z ? kb : qb;
  f32x4 acc[4][4] = {};
  for (int k0 = 0; k0 < 1024; k0 += 32) {
    __syncthreads();
    stage(As, A + k0, 1024, t);
    stage(Bs, B + k0, 1024, t);
    __syncthreads();
    mfma_tile(As, Bs, wr, wc, q8, r, acc);
  }
#pragma unroll
  for (int sn = 0; sn < 4; ++sn) {
    const int col = n0 + wc + sn * 16 + r;
    const float bc = bias[col];
#pragma unroll
    for (int sm = 0; sm < 4; ++sm)
#pragma unroll
      for (int i = 0; i < 4; ++i) {
        const int gm = m0 + wr + sm * 16 + (q << 2) + i;
        outp[(size_t)gm * 1024 + col] = f2b(acc[sm][sn][i] + bc);
      }
  }
}

// vT[b][d][l] and kTw[b][hd][l] via swapped GEMM. z: sel = z>>1 (0=vT, 1=kTw), b = z&1.
__global__ __launch_bounds__(256) void g_vtkt(const u16* __restrict__ xb, const u16* __restrict__ wvT,
    const u16* __restrict__ wkT, const float* __restrict__ bv, const float* __restrict__ bk,
    const float* __restrict__ wdl, u16* __restrict__ vT, u16* __restrict__ kTw) {
  __shared__ u16 As[4096], Bs[4096];
  TILE_IDS
  const int m0 = blockIdx.x * 128, l0 = blockIdx.y * 128;
  const int sel = blockIdx.z >> 1, b = blockIdx.z & 1;
  const u16* A = (sel ? wkT : wvT) + (size_t)m0 * 1024;
  const u16* B = xb + ((size_t)(b * 2048 + l0)) * 1024;
  f32x4 acc[4][4] = {};
  for (int k0 = 0; k0 < 1024; k0 += 32) {
    __syncthreads();
    stage(As, A + k0, 1024, t);
    stage(Bs, B + k0, 1024, t);
    __syncthreads();
    mfma_tile(As, Bs, wr, wc, q8, r, acc);
  }
#pragma unroll
  for (int sm = 0; sm < 4; ++sm)
#pragma unroll
    for (int i = 0; i < 4; ++i) {
      const int row = m0 + wr + sm * 16 + (q << 2) + i;  // d or hd
      const float bc = sel ? bk[row] : bv[row];
#pragma unroll
      for (int sn = 0; sn < 4; ++sn) {
        const int l = l0 + wc + sn * 16 + r;
        const float v = acc[sm][sn][i] + bc;
        if (!sel) {
          vT[((size_t)(b * 1024 + row)) * 2048 + l] = f2b(v);
        } else {
          const int n = row >> 7;
          kTw[((size_t)(b * 1024 + row)) * 2048 + l] =
              f2b(v * wdl[((size_t)(b * 8 + n)) * 2048 + l]);
        }
      }
    }
}

// S[bn][m][l] = -(q_m.k_l)*exp(lwd[m]*min(l+1,m)) for l<=m else 0. Triangular grid.
__global__ __launch_bounds__(256) void g2_s(const u16* __restrict__ qb, const u16* __restrict__ kb,
                                            const float* __restrict__ lwd, u16* __restrict__ S) {
  const int p = blockIdx.x, bn = blockIdx.y, b = bn >> 3, n = bn & 7;
  int mi = (int)((sqrtf(8.f * p + 1.f) - 1.f) * 0.5f);
  while ((mi + 1) * (mi + 2) / 2 <= p) ++mi;
  while (mi * (mi + 1) / 2 > p) --mi;
  const int li = p - mi * (mi + 1) / 2;
  const int m0 = mi * 128, l0 = li * 128;
  __shared__ u16 As[4096], Bs[4096];
  TILE_IDS
  const u16* A = qb + ((size_t)(b * 2048 + m0)) * 1024 + n * 128;
  const u16* B = kb + ((size_t)(b * 2048 + l0)) * 1024 + n * 128;
  f32x4 acc[4][4] = {};
  for (int k0 = 0; k0 < 128; k0 += 32) {
    __syncthreads();
    stage(As, A + k0, 1024, t);
    stage(Bs, B + k0, 1024, t);
    __syncthreads();
    mfma_tile(As, Bs, wr, wc, q8, r, acc);
  }
  const float* lwdp = lwd + (size_t)bn * 2048;
  u16* Sp = S + (size_t)bn * 2048 * 2048;
#pragma unroll
  for (int sm = 0; sm < 4; ++sm)
#pragma unroll
    for (int i = 0; i < 4; ++i) {
      const int m = m0 + wr + sm * 16 + (q << 2) + i;
      const float lm = lwdp[m];
#pragma unroll
      for (int sn = 0; sn < 4; ++sn) {
        const int l = l0 + wc + sn * 16 + r;
        float v = 0.f;
        if (l <= m) {
          const float c = (l == m) ? (float)m : (float)(l + 1);
          v = -acc[sm][sn][i] * __expf(lm * c);
        }
        Sp[(size_t)m * 2048 + l] = f2b(v);
      }
    }
}

// AfT[bn][d][l] = (sum_h hb[d,n*128+h]*kb[l,n*128+h] - vT[b,d,l]) * lr[bn,l]
__global__ __launch_bounds__(256) void g3_af(const u16* __restrict__ hb, const u16* __restrict__ kb,
                                             const u16* __restrict__ vT, const float* __restrict__ lr,
                                             u16* __restrict__ AfT) {
  const int d0 = blockIdx.x * 128, l0 = blockIdx.y * 128;
  const int bn = blockIdx.z, b = bn >> 3, n = bn & 7;
  __shared__ u16 As[4096], Bs[4096];
  TILE_IDS
  const u16* A = hb + ((size_t)(b * 1024 + d0)) * 1024 + n * 128;
  const u16* B = kb + ((size_t)(b * 2048 + l0)) * 1024 + n * 128;
  f32x4 acc[4][4] = {};
  for (int k0 = 0; k0 < 128; k0 += 32) {
    __syncthreads();
    stage(As, A + k0, 1024, t);
    stage(Bs, B + k0, 1024, t);
    __syncthreads();
    mfma_tile(As, Bs, wr, wc, q8, r, acc);
  }
  const float* lrp = lr + (size_t)bn * 2048;
#pragma unroll
  for (int sm = 0; sm < 4; ++sm)
#pragma unroll
    for (int i = 0; i < 4; ++i) {
      const int d = d0 + wr + sm * 16 + (q << 2) + i;
#pragma unroll
      for (int sn = 0; sn < 4; ++sn) {
        const int l = l0 + wc + sn * 16 + r;
        const float v = (acc[sm][sn][i] - b2f(vT[((size_t)(b * 1024 + d)) * 2048 + l])) * lrp[l];
        AfT[((size_t)bn * 1024 + d) * 2048 + l] = f2b(v);
      }
    }
}

// y partials: block (mip,dj,z={b,half}) does tiles mi=mip and 15-mip for heads
// half*4..+3 (triangular K over l) plus half of the cross GEMM K; atomicAdd into y.
__global__ __launch_bounds__(256) void g4(const u16* __restrict__ S, const u16* __restrict__ AfT,
                                          const u16* __restrict__ Qs, const u16* __restrict__ hb,
                                          float* __restrict__ y) {
  TILE_IDS
  const int mip = blockIdx.x, dj = blockIdx.y, z = blockIdx.z;
  const int b = z >> 1, half = z & 1;
  const int d0 = dj * 128;
  __shared__ u16 As[4096], Bs[4096];
  float* Y = y + (size_t)b * 2048 * 1024;
#pragma unroll 1
  for (int tsel = 0; tsel < 2; ++tsel) {
    const int mi = tsel ? (15 - mip) : mip;
    const int m0 = mi * 128;
    f32x4 acc[4][4] = {};
    for (int nh = 0; nh < 4; ++nh) {
      const int bn = b * 8 + half * 4 + nh;
      const u16* A = S + (size_t)bn * 2048 * 2048 + (size_t)m0 * 2048;
      const u16* B = AfT + ((size_t)bn * 1024 + d0) * 2048;
      const int nk = 4 * mi + 4;
      for (int c = 0; c < nk; ++c) {
        const int k0 = c * 32;
        __syncthreads();
        stage(As, A + k0, 2048, t);
        stage(Bs, B + k0, 2048, t);
        __syncthreads();
        mfma_tile(As, Bs, wr, wc, q8, r, acc);
      }
    }
    const u16* A2 = Qs + ((size_t)(b * 2048 + m0)) * 1024 + half * 512;
    const u16* B2 = hb + ((size_t)(b * 1024 + d0)) * 1024 + half * 512;
    for (int c = 0; c < 16; ++c) {
      const int k0 = c * 32;
      __syncthreads();
      stage(As, A2 + k0, 1024, t);
      stage(Bs, B2 + k0, 1024, t);
      __syncthreads();
      mfma_tile(As, Bs, wr, wc, q8, r, acc);
    }
#pragma unroll
    for (int sm = 0; sm < 4; ++sm)
#pragma unroll
      for (int i = 0; i < 4; ++i) {
        const int m = m0 + wr + sm * 16 + (q << 2) + i;
#pragma unroll
        for (int sn = 0; sn < 4; ++sn)
          atomicAdd(&Y[(size_t)m * 1024 + d0 + wc + sn * 16 + r], acc[sm][sn][i]);
      }
  }
}

// W_next[b][d][hd] = hidden*wdc_last - sum_l AfT[bn][d][l]*kTw[b][hd][l]
__global__ __launch_bounds__(256) void g5_wn(const u16* __restrict__ AfT, const u16* __restrict__ kTw,
                                             const float* __restrict__ wdc, const float* __restrict__ hidden,
                                             float* __restrict__ outw) {
  const int d0 = blockIdx.x * 128, nj = blockIdx.y, b = blockIdx.z;
  const int bn = b * 8 + nj;
  __shared__ u16 As[4096], Bs[4096];
  TILE_IDS
  const u16* A = AfT + ((size_t)bn * 1024 + d0) * 2048;
  const u16* B = kTw + ((size_t)(b * 1024 + nj * 128)) * 2048;
  f32x4 acc[4][4] = {};
  for (int k0 = 0; k0 < 2048; k0 += 32) {
    __syncthreads();
    stage(As, A + k0, 2048, t);
    stage(Bs, B + k0, 2048, t);
    __syncthreads();
    mfma_tile(As, Bs, wr, wc, q8, r, acc);
  }
  const float wdcl = wdc[(size_t)bn * 2048 + 2047];
#pragma unroll
  for (int sm = 0; sm < 4; ++sm)
#pragma unroll
    for (int i = 0; i < 4; ++i) {
      const int d = d0 + wr + sm * 16 + (q << 2) + i;
#pragma unroll
      for (int sn = 0; sn < 4; ++sn) {
        const int hd = nj * 128 + wc + sn * 16 + r;
        const size_t off = ((size_t)(b * 1024 + d)) * 1024 + hd;
        outw[off] = hidden[off] * wdcl - acc[sm][sn][i];
      }
    }
}

// ---------------- launch ----------------

extern "C" void kernel_launch(void* const* d_in, const int* in_sizes, int n_in,
                              void* d_out, int out_size, void* d_ws, size_t ws_size,
                              hipStream_t stream) {
  const float* x      = (const float*)d_in[0];
  const float* hidden = (const float*)d_in[1];
  const float* lbl    = (const float*)d_in[2];
  const float* wlr    = (const float*)d_in[3];
  const float* blr    = (const float*)d_in[4];
  const float* lbw    = (const float*)d_in[5];
  const float* wwd    = (const float*)d_in[6];
  const float* bwd    = (const float*)d_in[7];
  const float* wq     = (const float*)d_in[8];
  const float* bq     = (const float*)d_in[9];
  const float* wk     = (const float*)d_in[10];
  const float* bk     = (const float*)d_in[11];
  const float* wv     = (const float*)d_in[12];
  const float* bv     = (const float*)d_in[13];
  float* out = (float*)d_out;

  // Manual layout, 228.5 MB total (== R1's proven footprint).
  // Live ranges: xb/wqT/wkT/wvT die before g2_s writes S -> overlap them with S.
  char* ws = (char*)d_ws;
  const size_t MB = 1u << 20;
  u16* S     = (u16*)(ws);                 // [0,128MB)   g2_s -> g4
  u16* xb    = (u16*)(ws);                 // [0,8MB)     dead after g_vtkt
  u16* wqT   = (u16*)(ws + 8 * MB);        // [8,10)      dead after g_qk
  u16* wkT   = (u16*)(ws + 10 * MB);       // [10,12)     dead after g_vtkt
  u16* wvT   = (u16*)(ws + 12 * MB);       // [12,14)     dead after g_vtkt
  u16* AfT   = (u16*)(ws + 128 * MB);      // [128,192)
  u16* hb    = (u16*)(ws + 192 * MB);      // [192,196)
  u16* qb    = (u16*)(ws + 196 * MB);      // [196,204)   doubles as Qs after k_qs
  u16* kb    = (u16*)(ws + 204 * MB);      // [204,212)
  u16* kTw   = (u16*)(ws + 212 * MB);      // [212,220)
  u16* vT    = (u16*)(ws + 220 * MB);      // [220,228)
  float* lr  = (float*)(ws + 228 * MB);            // 128 KB
  float* lwd = (float*)(ws + 228 * MB + 131072);
  float* wdc = (float*)(ws + 228 * MB + 262144);
  float* wdl = (float*)(ws + 228 * MB + 393216);   // ends at 228.5 MB
  (void)ws_size; (void)n_in; (void)in_sizes; (void)out_size;

  const size_t YSZ = (size_t)2 * 2048 * 1024;

  k_cast<<<4096, 256, 0, stream>>>(x, xb);
  k_cast<<<2048, 256, 0, stream>>>(hidden, hb);
  k_twt<<<dim3(32, 32, 3), dim3(32, 8), 0, stream>>>(wq, wk, wv, wqT, wkT, wvT);
  k_lrwd<<<4096, 256, 0, stream>>>(x, wlr, blr, wwd, bwd, lbl, lbw, lr, lwd);
  k_scan<<<16, 256, 0, stream>>>(lwd, wdc, wdl);
  g_qk<<<dim3(32, 8, 2), 256, 0, stream>>>(xb, wqT, wkT, bq, bk, qb, kb);
  g_vtkt<<<dim3(8, 16, 4), 256, 0, stream>>>(xb, wvT, wkT, bv, bk, wdl, vT, kTw);
  g2_s<<<dim3(136, 16), 256, 0, stream>>>(qb, kb, lwd, S);   // clobbers xb/w*T (dead)
  k_qs<<<4096, 256, 0, stream>>>(qb, wdc);                   // qb -> Qs in place
  g3_af<<<dim3(8, 16, 16), 256, 0, stream>>>(hb, kb, vT, lr, AfT);
  k_zero<<<4096, 256, 0, stream>>>(out);                     // y := 0 for atomics
  g4<<<dim3(8, 8, 4), 256, 0, stream>>>(S, AfT, qb, hb, out);
  g5_wn<<<dim3(8, 8, 2), 256, 0, stream>>>(AfT, kTw, wdc, hidden, out + YSZ);
}